// Round 5
// baseline (100.387 us; speedup 1.0000x reference)
//
#include <hip/hip_runtime.h>

// NNSubmulti additive-attention block, MI355X (gfx950).
// B=16, TK=TQ=128, E=256, H=100.
//
// K1 prep_mfma: a[b,i,h] = (b1[h] + keys[b,i,:]·W1[h,:E]) * 2log2e
//               c[b,j,h] = (queries[b,j,:]·W1[h,E:])      * 2log2e
//               bf16 MFMA GEMM with inline f32->bf16 staging; pre-scaled by
//               2*log2(e) so attn's tanh uses exp2 directly.
//               Also converts Wlast -> Wb bf16 (512 elems/block).
// K2 attn_gemm: per block = batch b x 8 key-rows. sim -> softmax (1 wave/row)
//               -> p·queries -> features (bf16, LDS-resident) ->
//               relu(feat·Wlast^T + blast) via in-block MFMA -> d_out.

namespace {
constexpr int B  = 16;
constexpr int TQ = 128;
constexpr int TK = 128;
constexpr int E  = 256;
constexpr int H  = 100;
constexpr int HP = 112;   // padded H
constexpr int G  = 8;     // key-rows per attn block -> 256 blocks
constexpr float SC = 2.8853900817779268f;  // 2*log2(e)
}

typedef __attribute__((ext_vector_type(8))) short short8;   // 8 bf16
typedef __attribute__((ext_vector_type(4))) float f32x4;

__device__ __forceinline__ unsigned short f2bf(float f) {
  unsigned u = __builtin_bit_cast(unsigned, f);
  u = (u + 0x7FFFu + ((u >> 16) & 1u)) >> 16;   // round-to-nearest-even
  return (unsigned short)u;
}
__device__ __forceinline__ unsigned pk2(float x, float y) {
  return (unsigned)f2bf(x) | ((unsigned)f2bf(y) << 16);
}

// ---------------------------------------------------------------- K1 ----
// Block = 16 X-rows x 112 h. 7 N-tiles of 16, K=256 (8 mfma steps/tile).
__global__ __launch_bounds__(256) void prep_mfma(
    const float* __restrict__ queries, const float* __restrict__ keys,
    const float* __restrict__ W1, const float* __restrict__ b1,
    const float* __restrict__ Wlast,
    float* __restrict__ A, float* __restrict__ C,
    unsigned short* __restrict__ Wb) {
  __shared__ short Bs[112 * 264];   // 59.1 KB (+8-short row pad)
  __shared__ short As[16 * 264];    //  8.4 KB
  const int t  = threadIdx.x;
  const int m0 = blockIdx.x * 16;          // 256 blocks cover 4096 rows
  const bool isA = (m0 < B * TK);
  const int koff = isA ? 0 : 256;          // W1[:, :E] vs W1[:, E:]
  float* dst = isA ? (A + (size_t)m0 * HP)
                   : (C + (size_t)(m0 - B * TK) * HP);

  // Wlast f32 -> bf16 (256 blocks x 512 elems = 131072)
  {
    const int base = blockIdx.x * 512 + t * 2;
    float2 w = *(const float2*)(Wlast + base);
    *(unsigned*)(Wb + base) = pk2(w.x, w.y);
  }
  // stage+convert B: 112 rows x 32 chunks of 8 f32 (zeros for h>=100)
  #pragma unroll
  for (int i = 0; i < 14; ++i) {
    const int idx = i * 256 + t;
    const int h = idx >> 5, seg = idx & 31;
    uint4 o = make_uint4(0u, 0u, 0u, 0u);
    if (h < H) {
      const float4* p = (const float4*)(W1 + (size_t)h * 512 + koff + seg * 8);
      float4 u = p[0], v = p[1];
      o = make_uint4(pk2(u.x, u.y), pk2(u.z, u.w), pk2(v.x, v.y), pk2(v.z, v.w));
    }
    *(uint4*)(Bs + h * 264 + seg * 8) = o;
  }
  // stage+convert A: 16 rows x 32 chunks of 8 f32
  #pragma unroll
  for (int i = 0; i < 2; ++i) {
    const int idx = i * 256 + t;
    const int r = idx >> 5, seg = idx & 31;
    const float* src = isA ? (keys + (size_t)(m0 + r) * E)
                           : (queries + (size_t)(m0 - B * TK + r) * E);
    const float4* p = (const float4*)(src + seg * 8);
    float4 u = p[0], v = p[1];
    *(uint4*)(As + r * 264 + seg * 8) =
        make_uint4(pk2(u.x, u.y), pk2(u.z, u.w), pk2(v.x, v.y), pk2(v.z, v.w));
  }
  __syncthreads();

  const int wave = t >> 6, lane = t & 63;
  const int m = lane & 15, kq = lane >> 4;
  const int nt0 = wave, nt1 = wave + 4;    // tiles {w, w+4}; wave3: 1 tile
  f32x4 acc0 = {0.f, 0.f, 0.f, 0.f}, acc1 = {0.f, 0.f, 0.f, 0.f};

  #pragma unroll
  for (int kc = 0; kc < 8; ++kc) {
    short8 a = *(const short8*)(As + m * 264 + kc * 32 + kq * 8);
    short8 bv0 = *(const short8*)(Bs + (nt0 * 16 + m) * 264 + kc * 32 + kq * 8);
    acc0 = __builtin_amdgcn_mfma_f32_16x16x32_bf16(a, bv0, acc0, 0, 0, 0);
    if (nt1 < 7) {
      short8 bv1 = *(const short8*)(Bs + (nt1 * 16 + m) * 264 + kc * 32 + kq * 8);
      acc1 = __builtin_amdgcn_mfma_f32_16x16x32_bf16(a, bv1, acc1, 0, 0, 0);
    }
  }

  // epilogue: D col=lane&15 -> h (N), row=(lane>>4)*4+reg -> X-row (M)
  const int rbase = (lane >> 4) * 4;
  {
    const int h = nt0 * 16 + m;
    const float bias = (isA && h < H) ? b1[h] : 0.0f;
    #pragma unroll
    for (int r = 0; r < 4; ++r)
      dst[(size_t)(rbase + r) * HP + h] = (acc0[r] + bias) * SC;
  }
  if (nt1 < 7) {
    const int h = nt1 * 16 + m;
    const float bias = (isA && h < H) ? b1[h] : 0.0f;
    #pragma unroll
    for (int r = 0; r < 4; ++r)
      dst[(size_t)(rbase + r) * HP + h] = (acc1[r] + bias) * SC;
  }
}

// ---------------------------------------------------------------- K2 ----
__global__ __launch_bounds__(512) void attn_gemm(
    const float* __restrict__ queries, const float* __restrict__ keys,
    const float* __restrict__ qmask, const float* __restrict__ kmask,
    const float* __restrict__ W2, const float* __restrict__ blast,
    const float* __restrict__ A, const float* __restrict__ C,
    const unsigned short* __restrict__ Wb, float* __restrict__ out) {
  __shared__ float a_s[G * HP];              // 3.6 KB (pre-scaled a rows)
  __shared__ float w2s[HP];
  __shared__ float qm[TQ];
  __shared__ float simP[G * 512];            // 16 KB
  __shared__ float pL[G * TQ];               //  4 KB
  __shared__ short featL[16 * 520];          // 16.6 KB bf16 (rows 8..15 zero)

  const int t   = threadIdx.x;
  const int blk = blockIdx.x;                // 256 blocks
  const int b   = blk >> 4;                  // 16 blocks per batch
  const int i0  = (blk & 15) * G;

  // ---- stage ----
  if (t < G * HP / 4)
    ((float4*)a_s)[t] = ((const float4*)(A + ((size_t)b * TK + i0) * HP))[t];
  if (t < HP) w2s[t] = (t < H) ? W2[t] : 0.0f;
  if (t < TQ) qm[t]  = qmask[b * TQ + t];
  #pragma unroll
  for (int i = 0; i < 2; ++i) {              // zero featL rows 8..15
    int idx = t + i * 512;
    if (idx < 520) ((uint4*)(featL + 8 * 520))[idx] = make_uint4(0u, 0u, 0u, 0u);
  }
  __syncthreads();

  // ---- phase 1: sim partials (args pre-scaled by 2log2e -> exp2 direct) ----
  const int j = t & (TQ - 1);
  const int q = t >> 7;                      // h-quarter 0..3
  float4 cr[7], wr[7];
  float wsum = 0.0f;
  {
    const float4* c4 = (const float4*)(C + ((size_t)b * TQ + j) * HP + q * 28);
    const float4* w4 = (const float4*)w2s + q * 7;
    #pragma unroll
    for (int k = 0; k < 7; ++k) {
      cr[k] = c4[k];
      wr[k] = w4[k];
      wsum += wr[k].x + wr[k].y + wr[k].z + wr[k].w;
    }
  }
  {
    const float4* a4p = (const float4*)a_s + q * 7;
    #pragma unroll
    for (int g = 0; g < G; ++g) {
      float s = 0.0f;                        // s = sum_h w[h]*rcp(exp2(xs)+1)
      #pragma unroll
      for (int k = 0; k < 7; ++k) {
        float4 a4 = a4p[g * 28 + k];         // wave-uniform broadcast
        s = fmaf(wr[k].x, __builtin_amdgcn_rcpf(exp2f(a4.x + cr[k].x) + 1.0f), s);
        s = fmaf(wr[k].y, __builtin_amdgcn_rcpf(exp2f(a4.y + cr[k].y) + 1.0f), s);
        s = fmaf(wr[k].z, __builtin_amdgcn_rcpf(exp2f(a4.z + cr[k].z) + 1.0f), s);
        s = fmaf(wr[k].w, __builtin_amdgcn_rcpf(exp2f(a4.w + cr[k].w) + 1.0f), s);
      }
      simP[g * 512 + t] = wsum - 2.0f * s;   // quarter's sum_h w*tanh
    }
  }
  __syncthreads();

  // ---- phase 2: softmax, one wave per row g ----
  {
    const int g = t >> 6, lane = t & 63;
    const float* sp = simP + g * 512;
    float sv0 = sp[lane]      + sp[128 + lane]      + sp[256 + lane]      + sp[384 + lane];
    float sv1 = sp[lane + 64] + sp[128 + lane + 64] + sp[256 + lane + 64] + sp[384 + lane + 64];
    if (qm[lane] == 0.0f)      sv0 = -4294967295.0f;
    if (qm[lane + 64] == 0.0f) sv1 = -4294967295.0f;
    float p0 = __expf(sv0), p1 = __expf(sv1);   // |sim| <= sum|W2| ~ 24: safe
    float s = p0 + p1;
    #pragma unroll
    for (int off = 1; off < 64; off <<= 1) s += __shfl_xor(s, off, 64);
    float inv = __builtin_amdgcn_rcpf(s);
    pL[g * TQ + lane]      = p0 * inv;
    pL[g * TQ + lane + 64] = p1 * inv;
  }
  __syncthreads();

  // ---- phase 3: keys_attn + features (each thread: one e, 4 g-rows) ----
  {
    const int e = t & 255, gh = t >> 8;        // gh -> g in [gh*4, gh*4+4)
    float ka[4] = {0.f, 0.f, 0.f, 0.f};
    const float* qb = queries + (size_t)b * TQ * E + e;
    const float4* p4 = (const float4*)pL + (gh * 4) * 32;
    for (int j4 = 0; j4 < TQ / 4; ++j4) {
      float4 pv[4];
      #pragma unroll
      for (int gg = 0; gg < 4; ++gg) pv[gg] = p4[gg * 32 + j4];
      #pragma unroll
      for (int c = 0; c < 4; ++c) {
        float qv = qb[(size_t)(j4 * 4 + c) * E];   // coalesced
        #pragma unroll
        for (int gg = 0; gg < 4; ++gg)
          ka[gg] = fmaf(((const float*)&pv[gg])[c], qv, ka[gg]);
      }
    }
    #pragma unroll
    for (int gg = 0; gg < 4; ++gg) {
      const int g = gh * 4 + gg;
      const float kmv = kmask[b * TK + i0 + g];
      const float kav = ka[gg] * kmv;
      const float kv  = keys[((size_t)b * TK + i0 + g) * E + e];
      featL[g * 520 + e]     = (short)f2bf(kav * kv);   // feature_mul
      float d = kav - kv;
      featL[g * 520 + E + e] = (short)f2bf(d * d);      // feature_sub
    }
  }
  __syncthreads();

  // ---- phase 4: out = relu(feat·Wlast^T + blast); 8 waves x 32 N-cols ----
  {
    const int wave = t >> 6, lane = t & 63;
    const int m = lane & 15, kq = lane >> 4;
    f32x4 acc[2] = {{0.f, 0.f, 0.f, 0.f}, {0.f, 0.f, 0.f, 0.f}};
    #pragma unroll
    for (int kc = 0; kc < 16; ++kc) {          // K=512, 32 per step
      short8 a = *(const short8*)(featL + m * 520 + kc * 32 + kq * 8);
      #pragma unroll
      for (int nt = 0; nt < 2; ++nt) {
        const int ncol = wave * 32 + nt * 16 + m;
        short8 bf = *(const short8*)(Wb + (size_t)ncol * 512 + kc * 32 + kq * 8);
        acc[nt] = __builtin_amdgcn_mfma_f32_16x16x32_bf16(a, bf, acc[nt], 0, 0, 0);
      }
    }
    const int rbase = (lane >> 4) * 4;         // D rows; valid rows 0..7
    if (rbase < 8) {
      #pragma unroll
      for (int nt = 0; nt < 2; ++nt) {
        const int ncol = wave * 32 + nt * 16 + (lane & 15);
        const float bl = blast[ncol];
        #pragma unroll
        for (int r = 0; r < 4; ++r)
          out[((size_t)b * TK + i0 + rbase + r) * E + ncol] =
              fmaxf(acc[nt][r] + bl, 0.0f);
      }
    }
  }
}

// ------------------------------------------------------------- launch ----
extern "C" void kernel_launch(void* const* d_in, const int* in_sizes, int n_in,
                              void* d_out, int out_size, void* d_ws, size_t ws_size,
                              hipStream_t stream) {
  (void)in_sizes; (void)n_in; (void)out_size; (void)ws_size;
  const float* queries = (const float*)d_in[0];
  const float* keys    = (const float*)d_in[1];
  const float* qmask   = (const float*)d_in[2];
  const float* kmask   = (const float*)d_in[3];
  const float* W1      = (const float*)d_in[4];
  const float* b1      = (const float*)d_in[5];
  const float* W2      = (const float*)d_in[6];
  const float* Wlast   = (const float*)d_in[7];
  const float* blast   = (const float*)d_in[8];
  float* out = (float*)d_out;

  float* A = (float*)d_ws;                               // [2048][112] f32
  float* C = A + (size_t)B * TK * HP;                    // [2048][112] f32
  unsigned short* Wb = (unsigned short*)(C + (size_t)B * TQ * HP); // [256][512]
  // ws usage ~2.1 MiB

  prep_mfma<<<dim3(256), dim3(256), 0, stream>>>(
      queries, keys, W1, b1, Wlast, A, C, Wb);
  attn_gemm<<<dim3(B * (TK / G)), dim3(512), 0, stream>>>(
      queries, keys, qmask, kmask, W2, blast, A, C, Wb, out);
}